// Round 17
// baseline (389.083 us; speedup 1.0000x reference)
//
#include <hip/hip_runtime.h>
#include <hip/hip_fp16.h>
#include <stdint.h>

typedef _Float16 f16;
typedef _Float16 f16x4 __attribute__((ext_vector_type(4)));
typedef _Float16 f16x8 __attribute__((ext_vector_type(8)));
typedef float f32x4 __attribute__((ext_vector_type(4)));

__device__ __forceinline__ float fpq(float t) {
    float r = rintf(t * 256.0f);
    r = fminf(fmaxf(r, -32768.0f), 32767.0f);
    return r * 0.00390625f;
}

// swizzle key for 64-f16 rows (8 slots of 16B): bits {0,1,3}
__device__ __forceinline__ int swzkey(int r) { return (r & 3) | ((r >> 1) & 4); }
// swizzle key for 32-f16 rows (4 slots of 16B): verified 0 conflicts (r12)
__device__ __forceinline__ int kk2(int r) { return (r >> 1) & 3; }

__device__ __forceinline__ void gll16(const f16* g, f16* l) {
    __builtin_amdgcn_global_load_lds(
        (const __attribute__((address_space(1))) uint32_t*)g,
        (__attribute__((address_space(3))) uint32_t*)l, 16, 0, 0);
}

template <int N> __device__ __forceinline__ void waitvm() {
    if constexpr (N == 0)      asm volatile("s_waitcnt vmcnt(0)" ::: "memory");
    else if constexpr (N == 1) asm volatile("s_waitcnt vmcnt(1)" ::: "memory");
    else if constexpr (N == 2) asm volatile("s_waitcnt vmcnt(2)" ::: "memory");
    else if constexpr (N == 4) asm volatile("s_waitcnt vmcnt(4)" ::: "memory");
    else if constexpr (N == 6) asm volatile("s_waitcnt vmcnt(6)" ::: "memory");
    else                       asm volatile("s_waitcnt vmcnt(8)" ::: "memory");
}

// ---------------- LayerNorm: fp32 row (1024) -> fp16 row ----------------
__global__ __launch_bounds__(256) void ln_kernel(
        const float* __restrict__ x, const float* __restrict__ g,
        const float* __restrict__ b, f16* __restrict__ out) {
    int row = blockIdx.x;
    int t = threadIdx.x;
    const float4* xr = (const float4*)(x + (size_t)row * 1024);
    float4 v = xr[t];
    float s = v.x + v.y + v.z + v.w;
    float s2 = v.x * v.x + v.y * v.y + v.z * v.z + v.w * v.w;
#pragma unroll
    for (int o = 32; o >= 1; o >>= 1) {
        s += __shfl_down(s, o);
        s2 += __shfl_down(s2, o);
    }
    __shared__ float red[8];
    int wid = t >> 6;
    if ((t & 63) == 0) { red[wid] = s; red[4 + wid] = s2; }
    __syncthreads();
    float ts = red[0] + red[1] + red[2] + red[3];
    float ts2 = red[4] + red[5] + red[6] + red[7];
    float mu = ts * (1.0f / 1024.0f);
    float var = ts2 * (1.0f / 1024.0f) - mu * mu;
    float rs = rsqrtf(var + 1e-5f);
    float4 gg = ((const float4*)g)[t];
    float4 bb = ((const float4*)b)[t];
    f16x4 o4;
    o4[0] = (f16)((v.x - mu) * rs * gg.x + bb.x);
    o4[1] = (f16)((v.y - mu) * rs * gg.y + bb.y);
    o4[2] = (f16)((v.z - mu) * rs * gg.z + bb.z);
    o4[3] = (f16)((v.w - mu) * rs * gg.w + bb.w);
    ((f16x4*)out)[(size_t)row * 256 + t] = o4;
}

// ---------------- W [K,N] fp32 -> WT [N,K] fp16 ----------------
__global__ __launch_bounds__(256) void transpose_kernel(
        const float* __restrict__ W, f16* __restrict__ WT, int K, int N) {
    __shared__ float tile[32][33];
    int n0 = blockIdx.x * 32, k0 = blockIdx.y * 32;
    int tx = threadIdx.x & 31, ty = threadIdx.x >> 5;
#pragma unroll
    for (int i = 0; i < 32; i += 8)
        tile[ty + i][tx] = W[(size_t)(k0 + ty + i) * N + n0 + tx];
    __syncthreads();
#pragma unroll
    for (int i = 0; i < 32; i += 8)
        WT[(size_t)(n0 + ty + i) * K + k0 + tx] = (f16)tile[tx][ty + i];
}

// ---------------- 4-blocks/CU pipelined GEMM, supertile L2 decode -------------
// BM=BN=128, BK=32, 256 threads (4 waves 2x2, wave-tile 64x64). LDS 32 KB ->
// 4 blocks/CU (16 waves): TLP covers barrier/latency gaps. Counted vmcnt(4)
// double-buffer (never drain to 0 until tail). 8x8 supertile tile-order.
template <int EPI>
__global__ __launch_bounds__(256, 4) void gemmd_kernel(
        const f16* __restrict__ A, const f16* __restrict__ BT,
        int N, int K, int GM, int GN,
        const float* __restrict__ bias, const float* __restrict__ resid,
        void* __restrict__ out0, f16* __restrict__ outk, f16* __restrict__ outv) {
    constexpr int ABUF = 128 * 32;               // 4096 f16 (8 KB)
    constexpr int BUFSZ = 2 * ABUF;              // A+B = 16 KB
    __shared__ f16 lds[2 * BUFSZ];               // 32 KB -> 4 blocks/CU

    int nwg = GM * GN;
    int orig = blockIdx.x;
    int wg = (orig & 7) * (nwg >> 3) + (orig >> 3);   // contiguous wg chunk per XCD
    // supertile decode: 64 consecutive wg = 8 bm x 8 bn panels (L2-resident)
    int st = wg >> 6, in = wg & 63;
    int bm = (st % (GM >> 3)) * 8 + (in >> 3);
    int bn = (st / (GM >> 3)) * 8 + (in & 7);
    int m0 = bm * 128, n0 = bn * 128;
    int tid = threadIdx.x;
    int lane = tid & 63;
    int lr = lane & 15, lg = lane >> 4;
    int wv = tid >> 6;
    int wm = wv >> 1, wn = wv & 1;

    // staging: pre-inverse-swizzled global sources + linear LDS dests
    size_t srcA[2], srcB[2]; int dst[2];
#pragma unroll
    for (int j = 0; j < 2; ++j) {
        int row = j * 64 + (tid >> 2);
        int slot = (tid & 3) ^ kk2(row);
        srcA[j] = (size_t)(m0 + row) * K + slot * 8;
        srcB[j] = (size_t)(n0 + row) * K + slot * 8;
        dst[j] = j * 2048 + tid * 8;
    }

    // swizzled ds_read offsets (f16 elems, buffer-relative)
    int offA[4], offB[4];
#pragma unroll
    for (int i = 0; i < 4; ++i) {
        int row = wm * 64 + i * 16 + lr;
        offA[i] = row * 32 + ((lg ^ kk2(row)) * 8);
        int n = wn * 64 + i * 16 + lr;
        offB[i] = ABUF + n * 32 + ((lg ^ kk2(n)) * 8);
    }

    f32x4 acc[4][4] = {};
    int NT = K >> 5;

    // prologue: stage tiles 0 -> buf0, 1 -> buf1 (4 gll each)
#pragma unroll
    for (int j = 0; j < 2; ++j) gll16(A + srcA[j], lds + dst[j]);
#pragma unroll
    for (int j = 0; j < 2; ++j) gll16(BT + srcB[j], lds + ABUF + dst[j]);
#pragma unroll
    for (int j = 0; j < 2; ++j) gll16(A + srcA[j] + 32, lds + BUFSZ + dst[j]);
#pragma unroll
    for (int j = 0; j < 2; ++j) gll16(BT + srcB[j] + 32, lds + BUFSZ + ABUF + dst[j]);
    waitvm<4>();                      // tile 0 landed; tile 1 (4 loads) in flight
    __builtin_amdgcn_s_barrier();
    __builtin_amdgcn_sched_barrier(0);

    for (int t = 0; t < NT; ++t) {
        f16* Ab = lds + (t & 1) * BUFSZ;
        // ---- read all fragments of tile t ----
        f16x8 af[4], bf[4];
#pragma unroll
        for (int i = 0; i < 4; ++i) af[i] = *(const f16x8*)&Ab[offA[i]];
#pragma unroll
        for (int j = 0; j < 4; ++j) bf[j] = *(const f16x8*)&Ab[offB[j]];
        asm volatile("s_waitcnt lgkmcnt(0)" ::: "memory");   // buf cur fully read
        __builtin_amdgcn_sched_barrier(0);
        __builtin_amdgcn_s_barrier();                        // all waves done reading
        // ---- stage tile t+2 into buf cur (overlapped with MFMA) ----
        if (t + 2 < NT) {
            size_t kof = (size_t)(t + 2) << 5;
#pragma unroll
            for (int j = 0; j < 2; ++j) gll16(A + srcA[j] + kof, Ab + dst[j]);
#pragma unroll
            for (int j = 0; j < 2; ++j) gll16(BT + srcB[j] + kof, Ab + ABUF + dst[j]);
        }
        // ---- 16 MFMA ----
        __builtin_amdgcn_s_setprio(1);
#pragma unroll
        for (int i = 0; i < 4; ++i)
#pragma unroll
            for (int j = 0; j < 4; ++j)
                acc[i][j] = __builtin_amdgcn_mfma_f32_16x16x32_f16(af[i], bf[j], acc[i][j], 0, 0, 0);
        __builtin_amdgcn_s_setprio(0);
        // ---- tile boundary: counted wait (t+2's 4 loads stay in flight) ----
        if (t + 2 < NT) { waitvm<4>(); }
        else if (t + 1 < NT) { waitvm<0>(); }
        __builtin_amdgcn_sched_barrier(0);
        __builtin_amdgcn_s_barrier();
    }

    // epilogue
#pragma unroll
    for (int i = 0; i < 4; ++i) {
#pragma unroll
        for (int j = 0; j < 4; ++j) {
            int col = n0 + wn * 64 + j * 16 + lr;
            float bv = bias[col];
#pragma unroll
            for (int r = 0; r < 4; ++r) {
                int row = m0 + wm * 64 + i * 16 + lg * 4 + r;
                float val = acc[i][j][r] + bv;
                if (EPI == 0) {
                    float qv = fpq(val);
                    int part = col >> 10, wi = col & 1023;
                    int hd = wi >> 6, d = wi & 63;
                    int bb = row >> 10, ss = row & 1023;
                    size_t bh = (size_t)(bb * 16 + hd);
                    if (part == 0) {
                        ((f16*)out0)[(bh * 1024 + ss) * 64 + d] = (f16)qv;
                    } else if (part == 1) {
                        // K: [bh][kt][srow][d ^ (key(srow)<<3)]
                        outk[bh * 65536 + (ss >> 6) * 4096 + (ss & 63) * 64 + (d ^ (swzkey(ss) << 3))] = (f16)qv;
                    } else {
                        // V^T: [bh][kt][d][(srow) ^ (key(d)<<3)]
                        outv[bh * 65536 + (ss >> 6) * 4096 + d * 64 + ((ss & 63) ^ (swzkey(d) << 3))] = (f16)qv;
                    }
                } else if (EPI == 2) {
                    float hv = fmaxf(fpq(val), 0.0f);
                    ((f16*)out0)[(size_t)row * N + col] = (f16)hv;
                } else {
                    float o = fpq(resid[(size_t)row * 1024 + col] + fpq(val));
                    ((float*)out0)[(size_t)row * 1024 + col] = o;
                }
            }
        }
    }
}

// ---------------- Fused attention: QBLK=128 (8 waves), dbuf K/V, const-shift --
__global__ __launch_bounds__(512) void attn_kernel(
        const f16* __restrict__ Q, const f16* __restrict__ Kg,
        const f16* __restrict__ Vt, f16* __restrict__ ctx) {
    int id = blockIdx.x;
    int qt = (id >> 3) & 7;
    int bh = (id >> 6) * 8 + (id & 7);   // same-bh blocks share XCD residue
    int b = bh >> 4, h = bh & 15;
    const f16* Qp = Q + ((size_t)bh * 1024 + (size_t)qt * 128) * 64;
    const f16* Kp = Kg + (size_t)bh * 65536;
    const f16* Vp = Vt + (size_t)bh * 65536;
    int t = threadIdx.x, lane = t & 63, w = t >> 6;   // w in [0,8)
    int lr = lane & 15, lg = lane >> 4;
    __shared__ f16 Ks[2][4096];
    __shared__ f16 Vs[2][4096];
    int so = t * 8;                      // 512 threads x 8 f16 = full 4096 tile

    const float L2E = 1.4426950408889634f;
    const float C0 = -24.0f * 1.4426950408889634f;

    f16x8 qf[2];
#pragma unroll
    for (int kk = 0; kk < 2; ++kk) {
        qf[kk] = *(const f16x8*)(Qp + (w * 16 + lr) * 64 + kk * 32 + lg * 8);
#pragma unroll
        for (int j = 0; j < 8; ++j) qf[kk][j] = qf[kk][j] * (f16)0.125f;
    }
    int koff[4][2], voff[4][2];
#pragma unroll
    for (int nf = 0; nf < 4; ++nf) {
        int rowv = 32 * (nf >> 1) + 8 * ((lr >> 2) ^ (2 * (nf & 1))) + 4 * (nf & 1) + (lr & 3);
#pragma unroll
        for (int kk = 0; kk < 2; ++kk)
            koff[nf][kk] = rowv * 64 + (((kk * 4 + lg) ^ swzkey(rowv)) * 8);
    }
#pragma unroll
    for (int db = 0; db < 4; ++db) {
        int d = db * 16 + lr;
#pragma unroll
        for (int kk = 0; kk < 2; ++kk)
            voff[db][kk] = d * 64 + (((kk * 4 + lg) ^ swzkey(d)) * 8);
    }

    // ---- pass 1: l = sum(exp(s - 24)); K double-buffered, counted vmcnt ----
    gll16(Kp + so, Ks[0] + so);
    float lsum = 0.0f;
    for (int kt = 0; kt < 16; ++kt) {
        int cur = kt & 1;
        if (kt < 15) {
            gll16(Kp + (kt + 1) * 4096 + so, Ks[cur ^ 1] + so);
            waitvm<1>();
        } else {
            waitvm<0>();
        }
        __builtin_amdgcn_sched_barrier(0);
        __builtin_amdgcn_s_barrier();
        f32x4 sc[4] = {};
#pragma unroll
        for (int kk = 0; kk < 2; ++kk)
#pragma unroll
            for (int nf = 0; nf < 4; ++nf) {
                f16x8 kf = *(const f16x8*)&Ks[cur][koff[nf][kk]];
                sc[nf] = __builtin_amdgcn_mfma_f32_16x16x32_f16(kf, qf[kk], sc[nf], 0, 0, 0);
            }
        float part = 0.0f;
#pragma unroll
        for (int nf = 0; nf < 4; ++nf)
#pragma unroll
            for (int r = 0; r < 4; ++r)
                part += __builtin_amdgcn_exp2f(fmaf(sc[nf][r], L2E, C0));
        lsum += part;
        __builtin_amdgcn_s_barrier();
    }
    lsum += __shfl_xor(lsum, 16);
    lsum += __shfl_xor(lsum, 32);
    float rl256 = 256.0f * __builtin_amdgcn_rcpf(lsum);

    // ---- pass 2: p = rint(e*rl256)/256, PV; K+V double-buffered ----
    f32x4 co[4] = {};
    const float inv256 = 0.00390625f;
    gll16(Kp + so, Ks[0] + so);
    gll16(Vp + so, Vs[0] + so);
    for (int kt = 0; kt < 16; ++kt) {
        int cur = kt & 1;
        if (kt < 15) {
            gll16(Kp + (kt + 1) * 4096 + so, Ks[cur ^ 1] + so);
            gll16(Vp + (kt + 1) * 4096 + so, Vs[cur ^ 1] + so);
            waitvm<2>();
        } else {
            waitvm<0>();
        }
        __builtin_amdgcn_sched_barrier(0);
        __builtin_amdgcn_s_barrier();
        f32x4 sc[4] = {};
#pragma unroll
        for (int kk = 0; kk < 2; ++kk)
#pragma unroll
            for (int nf = 0; nf < 4; ++nf) {
                f16x8 kf = *(const f16x8*)&Ks[cur][koff[nf][kk]];
                sc[nf] = __builtin_amdgcn_mfma_f32_16x16x32_f16(kf, qf[kk], sc[nf], 0, 0, 0);
            }
        uint32_t pk0[4], pk1[4];
#pragma unroll
        for (int nf = 0; nf < 4; ++nf) {
            float e0 = __builtin_amdgcn_exp2f(fmaf(sc[nf][0], L2E, C0));
            float e1 = __builtin_amdgcn_exp2f(fmaf(sc[nf][1], L2E, C0));
            float e2 = __builtin_amdgcn_exp2f(fmaf(sc[nf][2], L2E, C0));
            float e3 = __builtin_amdgcn_exp2f(fmaf(sc[nf][3], L2E, C0));
            float r0 = rintf(e0 * rl256);
            float r1 = rintf(e1 * rl256);
            float r2 = rintf(e2 * rl256);
            float r3 = rintf(e3 * rl256);
            pk0[nf] = __builtin_bit_cast(uint32_t,
                        __builtin_amdgcn_cvt_pkrtz(r0 * inv256, r1 * inv256));
            pk1[nf] = __builtin_bit_cast(uint32_t,
                        __builtin_amdgcn_cvt_pkrtz(r2 * inv256, r3 * inv256));
        }
#pragma unroll
        for (int kk = 0; kk < 2; ++kk) {
            uint4 fw;
            fw.x = pk0[2 * kk];
            fw.y = pk1[2 * kk];
            fw.z = __shfl_xor(pk0[2 * kk + 1], 32);
            fw.w = __shfl_xor(pk1[2 * kk + 1], 32);
            f16x8 pa = __builtin_bit_cast(f16x8, fw);
#pragma unroll
            for (int db = 0; db < 4; ++db) {
                f16x8 vb = *(const f16x8*)&Vs[cur][voff[db][kk]];
                co[db] = __builtin_amdgcn_mfma_f32_16x16x32_f16(pa, vb, co[db], 0, 0, 0);
            }
        }
        __builtin_amdgcn_s_barrier();
    }
#pragma unroll
    for (int db = 0; db < 4; ++db)
#pragma unroll
        for (int r = 0; r < 4; ++r) {
            int ss = qt * 128 + w * 16 + lg * 4 + r;
            ctx[((size_t)b * 1024 + ss) * 1024 + h * 64 + db * 16 + lr] = (f16)co[db][r];
        }
}

extern "C" void kernel_launch(void* const* d_in, const int* in_sizes, int n_in,
                              void* d_out, int out_size, void* d_ws, size_t ws_size,
                              hipStream_t stream) {
    const float* x     = (const float*)d_in[0];
    const float* Wqkv  = (const float*)d_in[1];
    const float* bqkv  = (const float*)d_in[2];
    const float* Wout  = (const float*)d_in[3];
    const float* bout  = (const float*)d_in[4];
    const float* W1    = (const float*)d_in[5];
    const float* b1    = (const float*)d_in[6];
    const float* W2    = (const float*)d_in[7];
    const float* b2    = (const float*)d_in[8];
    const float* g1    = (const float*)d_in[9];
    const float* beta1 = (const float*)d_in[10];
    const float* g2    = (const float*)d_in[11];
    const float* beta2 = (const float*)d_in[12];

    char* ws = (char*)d_ws;
    const size_t MB = 1ull << 20;
    f16*  q_h   = (f16*)(ws);             // 16 MB
    f16*  k_h   = (f16*)(ws + 16 * MB);   // 16 MB (swizzled tiled)
    f16*  vt_h  = (f16*)(ws + 32 * MB);   // 16 MB (V^T swizzled tiled)
    f16*  ctx_h = (f16*)(ws + 48 * MB);   // 16 MB
    f16*  h_h   = (f16*)(ws);             // 64 MB, reuses q/k/vt/ctx after attention path
    f16*  xn_h  = (f16*)(ws + 64 * MB);   // 16 MB (xn, later xn2)
    float* x1   = (float*)(ws + 80 * MB); // 32 MB
    f16*  wT    = (f16*)(ws + 112 * MB);  // 8 MB (transposed weight, reused per GEMM)

    // --- attention branch ---
    ln_kernel<<<8192, 256, 0, stream>>>(x, g1, beta1, xn_h);
    transpose_kernel<<<dim3(96, 32), 256, 0, stream>>>(Wqkv, wT, 1024, 3072);
    gemmd_kernel<0><<<1536, 256, 0, stream>>>(xn_h, wT, 3072, 1024, 64, 24, bqkv, nullptr, q_h, k_h, vt_h);
    attn_kernel<<<1024, 512, 0, stream>>>(q_h, k_h, vt_h, ctx_h);
    transpose_kernel<<<dim3(32, 32), 256, 0, stream>>>(Wout, wT, 1024, 1024);
    gemmd_kernel<1><<<512, 256, 0, stream>>>(ctx_h, wT, 1024, 1024, 64, 8, bout, x, x1, nullptr, nullptr);
    // --- MLP branch ---
    ln_kernel<<<8192, 256, 0, stream>>>(x1, g2, beta2, xn_h);
    transpose_kernel<<<dim3(128, 32), 256, 0, stream>>>(W1, wT, 1024, 4096);
    gemmd_kernel<2><<<2048, 256, 0, stream>>>(xn_h, wT, 4096, 1024, 64, 32, b1, nullptr, h_h, nullptr, nullptr);
    transpose_kernel<<<dim3(32, 128), 256, 0, stream>>>(W2, wT, 4096, 1024);
    gemmd_kernel<3><<<512, 256, 0, stream>>>(h_h, wT, 1024, 4096, 64, 8, b2, x1, d_out, nullptr, nullptr);
}

// Round 18
// 352.129 us; speedup vs baseline: 1.1049x; 1.1049x over previous
//
#include <hip/hip_runtime.h>
#include <hip/hip_fp16.h>
#include <stdint.h>

typedef _Float16 f16;
typedef _Float16 f16x4 __attribute__((ext_vector_type(4)));
typedef _Float16 f16x8 __attribute__((ext_vector_type(8)));
typedef float f32x4 __attribute__((ext_vector_type(4)));

__device__ __forceinline__ float fpq(float t) {
    float r = rintf(t * 256.0f);
    r = fminf(fmaxf(r, -32768.0f), 32767.0f);
    return r * 0.00390625f;
}

// swizzle key for 64-f16 rows (8 slots of 16B): bits {0,1,3}
__device__ __forceinline__ int swzkey(int r) { return (r & 3) | ((r >> 1) & 4); }

__device__ __forceinline__ void gll16(const f16* g, f16* l) {
    __builtin_amdgcn_global_load_lds(
        (const __attribute__((address_space(1))) uint32_t*)g,
        (__attribute__((address_space(3))) uint32_t*)l, 16, 0, 0);
}

template <int N> __device__ __forceinline__ void waitvm() {
    if constexpr (N == 0)      asm volatile("s_waitcnt vmcnt(0)" ::: "memory");
    else if constexpr (N == 1) asm volatile("s_waitcnt vmcnt(1)" ::: "memory");
    else if constexpr (N == 2) asm volatile("s_waitcnt vmcnt(2)" ::: "memory");
    else if constexpr (N == 4) asm volatile("s_waitcnt vmcnt(4)" ::: "memory");
    else if constexpr (N == 6) asm volatile("s_waitcnt vmcnt(6)" ::: "memory");
    else                       asm volatile("s_waitcnt vmcnt(8)" ::: "memory");
}

// ---------------- device bodies for fused small kernels ----------------
__device__ __forceinline__ void ln_body(
        const float* __restrict__ x, const float* __restrict__ g,
        const float* __restrict__ b, f16* __restrict__ out,
        int row, float* red) {
    int t = threadIdx.x;
    const float4* xr = (const float4*)(x + (size_t)row * 1024);
    float4 v = xr[t];
    float s = v.x + v.y + v.z + v.w;
    float s2 = v.x * v.x + v.y * v.y + v.z * v.z + v.w * v.w;
#pragma unroll
    for (int o = 32; o >= 1; o >>= 1) {
        s += __shfl_down(s, o);
        s2 += __shfl_down(s2, o);
    }
    int wid = t >> 6;
    if ((t & 63) == 0) { red[wid] = s; red[4 + wid] = s2; }
    __syncthreads();
    float ts = red[0] + red[1] + red[2] + red[3];
    float ts2 = red[4] + red[5] + red[6] + red[7];
    float mu = ts * (1.0f / 1024.0f);
    float var = ts2 * (1.0f / 1024.0f) - mu * mu;
    float rs = rsqrtf(var + 1e-5f);
    float4 gg = ((const float4*)g)[t];
    float4 bb = ((const float4*)b)[t];
    f16x4 o4;
    o4[0] = (f16)((v.x - mu) * rs * gg.x + bb.x);
    o4[1] = (f16)((v.y - mu) * rs * gg.y + bb.y);
    o4[2] = (f16)((v.z - mu) * rs * gg.z + bb.z);
    o4[3] = (f16)((v.w - mu) * rs * gg.w + bb.w);
    ((f16x4*)out)[(size_t)row * 256 + t] = o4;
}

__device__ __forceinline__ void tr_body(
        const float* __restrict__ W, f16* __restrict__ WT,
        int K, int N, int bx, int by, float* smem) {
    float (*tile)[33] = (float (*)[33])smem;
    int n0 = bx * 32, k0 = by * 32;
    int tx = threadIdx.x & 31, ty = threadIdx.x >> 5;
#pragma unroll
    for (int i = 0; i < 32; i += 8)
        tile[ty + i][tx] = W[(size_t)(k0 + ty + i) * N + n0 + tx];
    __syncthreads();
#pragma unroll
    for (int i = 0; i < 32; i += 8)
        WT[(size_t)(n0 + ty + i) * K + k0 + tx] = (f16)tile[tx][ty + i];
}

// ---------------- prologue: LN1 + T(Wqkv) + T(Wout) in one launch ------------
__global__ __launch_bounds__(256) void prologue_kernel(
        const float* __restrict__ x, const float* __restrict__ g1,
        const float* __restrict__ b1, f16* __restrict__ xn,
        const float* __restrict__ Wqkv, f16* __restrict__ wqkvT,
        const float* __restrict__ Wout, f16* __restrict__ woutT) {
    __shared__ float smem[32 * 33];
    int id = blockIdx.x;
    if (id < 8192) {
        ln_body(x, g1, b1, xn, id, smem);
    } else if (id < 8192 + 3072) {
        int q = id - 8192;
        tr_body(Wqkv, wqkvT, 1024, 3072, q % 96, q / 96, smem);
    } else {
        int q = id - (8192 + 3072);
        tr_body(Wout, woutT, 1024, 1024, q % 32, q / 32, smem);
    }
}

// ---------------- midlogue: LN2 + T(W1) [+ T(W2)] in one launch --------------
__global__ __launch_bounds__(256) void midlogue_kernel(
        const float* __restrict__ x1, const float* __restrict__ g2,
        const float* __restrict__ b2, f16* __restrict__ xn,
        const float* __restrict__ W1, f16* __restrict__ w1T,
        const float* __restrict__ W2, f16* __restrict__ w2T) {
    __shared__ float smem[32 * 33];
    int id = blockIdx.x;
    if (id < 8192) {
        ln_body(x1, g2, b2, xn, id, smem);
    } else if (id < 8192 + 4096) {
        int q = id - 8192;
        tr_body(W1, w1T, 1024, 4096, q % 128, q / 128, smem);
    } else {
        int q = id - (8192 + 4096);
        tr_body(W2, w2T, 4096, 1024, q % 32, q / 32, smem);
    }
}

// ---------------- standalone transpose (fallback for W2) ----------------
__global__ __launch_bounds__(256) void transpose_kernel(
        const float* __restrict__ W, f16* __restrict__ WT, int K, int N) {
    __shared__ float smem[32 * 33];
    tr_body(W, WT, K, N, blockIdx.x, blockIdx.y, smem);
}

// ---------------- 2-blocks/CU pipelined GEMM, supertile L2 decode (r16) ------
// BM=BN=128, BK=64, 256 threads (4 waves 2x2, wave-tile 64x64). LDS 64 KB ->
// 2 blocks/CU. Counted vmcnt(8) double-buffer. 8x8 supertile tile-order.
template <int EPI>
__global__ __launch_bounds__(256, 2) void gemmd_kernel(
        const f16* __restrict__ A, const f16* __restrict__ BT,
        int N, int K, int GM, int GN,
        const float* __restrict__ bias, const float* __restrict__ resid,
        void* __restrict__ out0, f16* __restrict__ outk, f16* __restrict__ outv) {
    constexpr int ABUF = 128 * 64;               // 8192 f16 (16 KB)
    constexpr int BUFSZ = 2 * ABUF;              // A+B = 32 KB
    __shared__ f16 lds[2 * BUFSZ];               // 64 KB

    int nwg = GM * GN;
    int orig = blockIdx.x;
    int wg = (orig & 7) * (nwg >> 3) + (orig >> 3);   // contiguous wg chunk per XCD
    // supertile decode: 64 consecutive wg = 8 bm x 8 bn panels (L2-resident)
    int st = wg >> 6, in = wg & 63;
    int bm = (st % (GM >> 3)) * 8 + (in >> 3);
    int bn = (st / (GM >> 3)) * 8 + (in & 7);
    int m0 = bm * 128, n0 = bn * 128;
    int tid = threadIdx.x;
    int lane = tid & 63;
    int lr = lane & 15, lg = lane >> 4;
    int wv = tid >> 6;
    int wm = wv >> 1, wn = wv & 1;

    // staging: pre-inverse-swizzled global sources + linear LDS dests
    size_t srcA[4], srcB[4]; int dst[4];
#pragma unroll
    for (int j = 0; j < 4; ++j) {
        int row = j * 32 + (tid >> 3);
        int slot = (tid & 7) ^ (row & 7);
        srcA[j] = (size_t)(m0 + row) * K + slot * 8;
        srcB[j] = (size_t)(n0 + row) * K + slot * 8;
        dst[j] = j * 2048 + tid * 8;
    }

    // swizzled ds_read offsets (f16 elements, buffer-relative)
    int offA[2][4], offB[4][2];
#pragma unroll
    for (int i = 0; i < 4; ++i) {
        int row = wm * 64 + i * 16 + lr;
#pragma unroll
        for (int kk = 0; kk < 2; ++kk)
            offA[kk][i] = row * 64 + (((kk * 4 + lg) ^ (row & 7)) * 8);
    }
#pragma unroll
    for (int j = 0; j < 4; ++j) {
        int n = wn * 64 + j * 16 + lr;
#pragma unroll
        for (int kk = 0; kk < 2; ++kk)
            offB[j][kk] = ABUF + n * 64 + (((kk * 4 + lg) ^ (n & 7)) * 8);
    }

    f32x4 acc[4][4] = {};
    int NT = K >> 6;

    // prologue: stage tiles 0 -> buf0, 1 -> buf1 (8 gll each)
#pragma unroll
    for (int j = 0; j < 4; ++j) gll16(A + srcA[j], lds + dst[j]);
#pragma unroll
    for (int j = 0; j < 4; ++j) gll16(BT + srcB[j], lds + ABUF + dst[j]);
#pragma unroll
    for (int j = 0; j < 4; ++j) gll16(A + srcA[j] + 64, lds + BUFSZ + dst[j]);
#pragma unroll
    for (int j = 0; j < 4; ++j) gll16(BT + srcB[j] + 64, lds + BUFSZ + ABUF + dst[j]);
    waitvm<8>();                      // tile 0 landed; tile 1 in flight
    __builtin_amdgcn_s_barrier();
    __builtin_amdgcn_sched_barrier(0);

    for (int t = 0; t < NT; ++t) {
        int cur = t & 1;
        f16* Ab = lds + cur * BUFSZ;
        // ---- all A-frags + cols 0,1 B-frags ----
        f16x8 a0[4], a1[4], b00, b01, b10, b11;
#pragma unroll
        for (int i = 0; i < 4; ++i) a0[i] = *(const f16x8*)&Ab[offA[0][i]];
        b00 = *(const f16x8*)&Ab[offB[0][0]];
        b01 = *(const f16x8*)&Ab[offB[1][0]];
#pragma unroll
        for (int i = 0; i < 4; ++i) a1[i] = *(const f16x8*)&Ab[offA[1][i]];
        b10 = *(const f16x8*)&Ab[offB[0][1]];
        b11 = *(const f16x8*)&Ab[offB[1][1]];
        // ---- cols 0,1 MFMA ----
        __builtin_amdgcn_s_setprio(1);
#pragma unroll
        for (int i = 0; i < 4; ++i) {
            acc[i][0] = __builtin_amdgcn_mfma_f32_16x16x32_f16(a0[i], b00, acc[i][0], 0, 0, 0);
            acc[i][1] = __builtin_amdgcn_mfma_f32_16x16x32_f16(a0[i], b01, acc[i][1], 0, 0, 0);
        }
#pragma unroll
        for (int i = 0; i < 4; ++i) {
            acc[i][0] = __builtin_amdgcn_mfma_f32_16x16x32_f16(a1[i], b10, acc[i][0], 0, 0, 0);
            acc[i][1] = __builtin_amdgcn_mfma_f32_16x16x32_f16(a1[i], b11, acc[i][1], 0, 0, 0);
        }
        __builtin_amdgcn_s_setprio(0);
        // ---- cols 2,3 B-frags (last reads of buf cur) ----
        f16x8 b20 = *(const f16x8*)&Ab[offB[2][0]];
        f16x8 b30 = *(const f16x8*)&Ab[offB[3][0]];
        f16x8 b21 = *(const f16x8*)&Ab[offB[2][1]];
        f16x8 b31 = *(const f16x8*)&Ab[offB[3][1]];
        asm volatile("s_waitcnt lgkmcnt(0)" ::: "memory");   // buf cur fully read
        __builtin_amdgcn_sched_barrier(0);
        __builtin_amdgcn_s_barrier();                        // all waves done reading
        // ---- stage tile t+2 into buf cur (overlapped with cols 2,3) ----
        if (t + 2 < NT) {
            size_t kof = (size_t)(t + 2) << 6;
#pragma unroll
            for (int j = 0; j < 4; ++j) gll16(A + srcA[j] + kof, Ab + dst[j]);
#pragma unroll
            for (int j = 0; j < 4; ++j) gll16(BT + srcB[j] + kof, Ab + ABUF + dst[j]);
        }
        // ---- cols 2,3 MFMA ----
        __builtin_amdgcn_s_setprio(1);
#pragma unroll
        for (int i = 0; i < 4; ++i) {
            acc[i][2] = __builtin_amdgcn_mfma_f32_16x16x32_f16(a0[i], b20, acc[i][2], 0, 0, 0);
            acc[i][3] = __builtin_amdgcn_mfma_f32_16x16x32_f16(a0[i], b30, acc[i][3], 0, 0, 0);
        }
#pragma unroll
        for (int i = 0; i < 4; ++i) {
            acc[i][2] = __builtin_amdgcn_mfma_f32_16x16x32_f16(a1[i], b21, acc[i][2], 0, 0, 0);
            acc[i][3] = __builtin_amdgcn_mfma_f32_16x16x32_f16(a1[i], b31, acc[i][3], 0, 0, 0);
        }
        __builtin_amdgcn_s_setprio(0);
        // ---- tile boundary: counted wait (t+2 still in flight) ----
        if (t + 2 < NT) { waitvm<8>(); }
        else if (t + 1 < NT) { waitvm<0>(); }
        __builtin_amdgcn_sched_barrier(0);
        __builtin_amdgcn_s_barrier();
    }

    // epilogue
#pragma unroll
    for (int i = 0; i < 4; ++i) {
#pragma unroll
        for (int j = 0; j < 4; ++j) {
            int col = n0 + wn * 64 + j * 16 + lr;
            float bv = bias[col];
#pragma unroll
            for (int r = 0; r < 4; ++r) {
                int row = m0 + wm * 64 + i * 16 + lg * 4 + r;
                float val = acc[i][j][r] + bv;
                if (EPI == 0) {
                    float qv = fpq(val);
                    int part = col >> 10, wi = col & 1023;
                    int hd = wi >> 6, d = wi & 63;
                    int bb = row >> 10, ss = row & 1023;
                    size_t bh = (size_t)(bb * 16 + hd);
                    if (part == 0) {
                        ((f16*)out0)[(bh * 1024 + ss) * 64 + d] = (f16)qv;
                    } else if (part == 1) {
                        // K: [bh][kt][srow][d ^ (key(srow)<<3)]
                        outk[bh * 65536 + (ss >> 6) * 4096 + (ss & 63) * 64 + (d ^ (swzkey(ss) << 3))] = (f16)qv;
                    } else {
                        // V^T: [bh][kt][d][(srow) ^ (key(d)<<3)]
                        outv[bh * 65536 + (ss >> 6) * 4096 + d * 64 + ((ss & 63) ^ (swzkey(d) << 3))] = (f16)qv;
                    }
                } else if (EPI == 2) {
                    float hv = fmaxf(fpq(val), 0.0f);
                    ((f16*)out0)[(size_t)row * N + col] = (f16)hv;
                } else {
                    float o = fpq(resid[(size_t)row * 1024 + col] + fpq(val));
                    ((float*)out0)[(size_t)row * 1024 + col] = o;
                }
            }
        }
    }
}

// ---------------- Fused attention: QBLK=128 (8 waves), dbuf K/V, const-shift --
__global__ __launch_bounds__(512) void attn_kernel(
        const f16* __restrict__ Q, const f16* __restrict__ Kg,
        const f16* __restrict__ Vt, f16* __restrict__ ctx) {
    int id = blockIdx.x;
    int qt = (id >> 3) & 7;
    int bh = (id >> 6) * 8 + (id & 7);   // same-bh blocks share XCD residue
    int b = bh >> 4, h = bh & 15;
    const f16* Qp = Q + ((size_t)bh * 1024 + (size_t)qt * 128) * 64;
    const f16* Kp = Kg + (size_t)bh * 65536;
    const f16* Vp = Vt + (size_t)bh * 65536;
    int t = threadIdx.x, lane = t & 63, w = t >> 6;   // w in [0,8)
    int lr = lane & 15, lg = lane >> 4;
    __shared__ f16 Ks[2][4096];
    __shared__ f16 Vs[2][4096];
    int so = t * 8;                      // 512 threads x 8 f16 = full 4096 tile

    const float L2E = 1.4426950408889634f;
    const float C0 = -24.0f * 1.4426950408889634f;

    f16x8 qf[2];
#pragma unroll
    for (int kk = 0; kk < 2; ++kk) {
        qf[kk] = *(const f16x8*)(Qp + (w * 16 + lr) * 64 + kk * 32 + lg * 8);
#pragma unroll
        for (int j = 0; j < 8; ++j) qf[kk][j] = qf[kk][j] * (f16)0.125f;
    }
    int koff[4][2], voff[4][2];
#pragma unroll
    for (int nf = 0; nf < 4; ++nf) {
        int rowv = 32 * (nf >> 1) + 8 * ((lr >> 2) ^ (2 * (nf & 1))) + 4 * (nf & 1) + (lr & 3);
#pragma unroll
        for (int kk = 0; kk < 2; ++kk)
            koff[nf][kk] = rowv * 64 + (((kk * 4 + lg) ^ swzkey(rowv)) * 8);
    }
#pragma unroll
    for (int db = 0; db < 4; ++db) {
        int d = db * 16 + lr;
#pragma unroll
        for (int kk = 0; kk < 2; ++kk)
            voff[db][kk] = d * 64 + (((kk * 4 + lg) ^ swzkey(d)) * 8);
    }

    // ---- pass 1: l = sum(exp(s - 24)); K double-buffered, counted vmcnt ----
    gll16(Kp + so, Ks[0] + so);
    float lsum = 0.0f;
    for (int kt = 0; kt < 16; ++kt) {
        int cur = kt & 1;
        if (kt < 15) {
            gll16(Kp + (kt + 1) * 4096 + so, Ks[cur ^ 1] + so);
            waitvm<1>();
        } else {
            waitvm<0>();
        }
        __builtin_amdgcn_sched_barrier(0);
        __builtin_amdgcn_s_barrier();
        f32x4 sc[4] = {};
#pragma unroll
        for (int kk = 0; kk < 2; ++kk)
#pragma unroll
            for (int nf = 0; nf < 4; ++nf) {
                f16x8 kf = *(const f16x8*)&Ks[cur][koff[nf][kk]];
                sc[nf] = __builtin_amdgcn_mfma_f32_16x16x32_f16(kf, qf[kk], sc[nf], 0, 0, 0);
            }
        float part = 0.0f;
#pragma unroll
        for (int nf = 0; nf < 4; ++nf)
#pragma unroll
            for (int r = 0; r < 4; ++r)
                part += __builtin_amdgcn_exp2f(fmaf(sc[nf][r], L2E, C0));
        lsum += part;
        __builtin_amdgcn_s_barrier();
    }
    lsum += __shfl_xor(lsum, 16);
    lsum += __shfl_xor(lsum, 32);
    float rl256 = 256.0f * __builtin_amdgcn_rcpf(lsum);

    // ---- pass 2: p = rint(e*rl256)/256, PV; K+V double-buffered ----
    f32x4 co[4] = {};
    const float inv256 = 0.00390625f;
    gll16(Kp + so, Ks[0] + so);
    gll16(Vp + so, Vs[0] + so);
    for (int kt = 0; kt < 16; ++kt) {
        int cur = kt & 1;
        if (kt < 15) {
            gll16(Kp + (kt + 1) * 4096 + so, Ks[cur ^ 1] + so);
            gll16(Vp + (kt + 1) * 4096 + so, Vs[cur ^ 1] + so);
            waitvm<2>();
        } else {
            waitvm<0>();
        }
        __builtin_amdgcn_sched_barrier(0);
        __builtin_amdgcn_s_barrier();
        f32x4 sc[4] = {};
#pragma unroll
        for (int kk = 0; kk < 2; ++kk)
#pragma unroll
            for (int nf = 0; nf < 4; ++nf) {
                f16x8 kf = *(const f16x8*)&Ks[cur][koff[nf][kk]];
                sc[nf] = __builtin_amdgcn_mfma_f32_16x16x32_f16(kf, qf[kk], sc[nf], 0, 0, 0);
            }
        uint32_t pk0[4], pk1[4];
#pragma unroll
        for (int nf = 0; nf < 4; ++nf) {
            float e0 = __builtin_amdgcn_exp2f(fmaf(sc[nf][0], L2E, C0));
            float e1 = __builtin_amdgcn_exp2f(fmaf(sc[nf][1], L2E, C0));
            float e2 = __builtin_amdgcn_exp2f(fmaf(sc[nf][2], L2E, C0));
            float e3 = __builtin_amdgcn_exp2f(fmaf(sc[nf][3], L2E, C0));
            float r0 = rintf(e0 * rl256);
            float r1 = rintf(e1 * rl256);
            float r2 = rintf(e2 * rl256);
            float r3 = rintf(e3 * rl256);
            pk0[nf] = __builtin_bit_cast(uint32_t,
                        __builtin_amdgcn_cvt_pkrtz(r0 * inv256, r1 * inv256));
            pk1[nf] = __builtin_bit_cast(uint32_t,
                        __builtin_amdgcn_cvt_pkrtz(r2 * inv256, r3 * inv256));
        }
#pragma unroll
        for (int kk = 0; kk < 2; ++kk) {
            uint4 fw;
            fw.x = pk0[2 * kk];
            fw.y = pk1[2 * kk];
            fw.z = __shfl_xor(pk0[2 * kk + 1], 32);
            fw.w = __shfl_xor(pk1[2 * kk + 1], 32);
            f16x8 pa = __builtin_bit_cast(f16x8, fw);
#pragma unroll
            for (int db = 0; db < 4; ++db) {
                f16x8 vb = *(const f16x8*)&Vs[cur][voff[db][kk]];
                co[db] = __builtin_amdgcn_mfma_f32_16x16x32_f16(pa, vb, co[db], 0, 0, 0);
            }
        }
        __builtin_amdgcn_s_barrier();
    }
#pragma unroll
    for (int db = 0; db < 4; ++db)
#pragma unroll
        for (int r = 0; r < 4; ++r) {
            int ss = qt * 128 + w * 16 + lg * 4 + r;
            ctx[((size_t)b * 1024 + ss) * 1024 + h * 64 + db * 16 + lr] = (f16)co[db][r];
        }
}

extern "C" void kernel_launch(void* const* d_in, const int* in_sizes, int n_in,
                              void* d_out, int out_size, void* d_ws, size_t ws_size,
                              hipStream_t stream) {
    const float* x     = (const float*)d_in[0];
    const float* Wqkv  = (const float*)d_in[1];
    const float* bqkv  = (const float*)d_in[2];
    const float* Wout  = (const float*)d_in[3];
    const float* bout  = (const float*)d_in[4];
    const float* W1    = (const float*)d_in[5];
    const float* b1    = (const float*)d_in[6];
    const float* W2    = (const float*)d_in[7];
    const float* b2    = (const float*)d_in[8];
    const float* g1    = (const float*)d_in[9];
    const float* beta1 = (const float*)d_in[10];
    const float* g2    = (const float*)d_in[11];
    const float* beta2 = (const float*)d_in[12];

    char* ws = (char*)d_ws;
    const size_t MB = 1ull << 20;
    f16*  q_h    = (f16*)(ws);             // 16 MB
    f16*  k_h    = (f16*)(ws + 16 * MB);   // 16 MB (swizzled tiled)
    f16*  vt_h   = (f16*)(ws + 32 * MB);   // 16 MB (V^T swizzled tiled)
    f16*  ctx_h  = (f16*)(ws + 48 * MB);   // 16 MB
    f16*  h_h    = (f16*)(ws);             // 64 MB, reuses q/k/vt/ctx after attention
    f16*  xn_h   = (f16*)(ws + 64 * MB);   // 16 MB (xn, later xn2)
    float* x1    = (float*)(ws + 80 * MB); // 32 MB
    f16*  wqkvT  = (f16*)(ws + 112 * MB);  // 6 MB (dead after gemm<0>)
    f16*  woutT  = (f16*)(ws + 118 * MB);  // 2 MB (dead after gemm<1>)
    f16*  w1T    = (f16*)(ws + 112 * MB);  // 8 MB (overwrites wqkvT/woutT post-g1)
    bool bigws   = ws_size >= (size_t)130 * MB;
    f16*  w2T    = bigws ? (f16*)(ws + 120 * MB) : (f16*)(ws + 112 * MB);

    // --- prologue: LN1 + T(Wqkv) + T(Wout), one launch ---
    prologue_kernel<<<8192 + 3072 + 1024, 256, 0, stream>>>(
        x, g1, beta1, xn_h, Wqkv, wqkvT, Wout, woutT);
    gemmd_kernel<0><<<1536, 256, 0, stream>>>(xn_h, wqkvT, 3072, 1024, 64, 24, bqkv, nullptr, q_h, k_h, vt_h);
    attn_kernel<<<1024, 512, 0, stream>>>(q_h, k_h, vt_h, ctx_h);
    gemmd_kernel<1><<<512, 256, 0, stream>>>(ctx_h, woutT, 1024, 1024, 64, 8, bout, x, x1, nullptr, nullptr);
    // --- midlogue: LN2 + T(W1) (+ T(W2) when ws allows a separate slot) ---
    midlogue_kernel<<<bigws ? (8192 + 4096 + 4096) : (8192 + 4096), 256, 0, stream>>>(
        x1, g2, beta2, xn_h, W1, w1T, W2, w2T);
    gemmd_kernel<2><<<2048, 256, 0, stream>>>(xn_h, w1T, 4096, 1024, 64, 32, b1, nullptr, h_h, nullptr, nullptr);
    if (!bigws)
        transpose_kernel<<<dim3(32, 128), 256, 0, stream>>>(W2, w2T, 4096, 1024);
    gemmd_kernel<3><<<512, 256, 0, stream>>>(h_h, w2T, 1024, 4096, 64, 8, b2, x1, d_out, nullptr, nullptr);
}

// Round 19
// 350.910 us; speedup vs baseline: 1.1088x; 1.0035x over previous
//
#include <hip/hip_runtime.h>
#include <hip/hip_fp16.h>
#include <stdint.h>

typedef _Float16 f16;
typedef _Float16 f16x4 __attribute__((ext_vector_type(4)));
typedef _Float16 f16x8 __attribute__((ext_vector_type(8)));
typedef float f32x4 __attribute__((ext_vector_type(4)));

__device__ __forceinline__ float fpq(float t) {
    float r = rintf(t * 256.0f);
    r = fminf(fmaxf(r, -32768.0f), 32767.0f);
    return r * 0.00390625f;
}

// swizzle key for 64-f16 rows (8 slots of 16B): bits {0,1,3}
__device__ __forceinline__ int swzkey(int r) { return (r & 3) | ((r >> 1) & 4); }

__device__ __forceinline__ void gll16(const f16* g, f16* l) {
    __builtin_amdgcn_global_load_lds(
        (const __attribute__((address_space(1))) uint32_t*)g,
        (__attribute__((address_space(3))) uint32_t*)l, 16, 0, 0);
}

template <int N> __device__ __forceinline__ void waitvm() {
    if constexpr (N == 0)      asm volatile("s_waitcnt vmcnt(0)" ::: "memory");
    else if constexpr (N == 1) asm volatile("s_waitcnt vmcnt(1)" ::: "memory");
    else if constexpr (N == 2) asm volatile("s_waitcnt vmcnt(2)" ::: "memory");
    else if constexpr (N == 4) asm volatile("s_waitcnt vmcnt(4)" ::: "memory");
    else if constexpr (N == 6) asm volatile("s_waitcnt vmcnt(6)" ::: "memory");
    else                       asm volatile("s_waitcnt vmcnt(8)" ::: "memory");
}

// ---------------- device bodies for fused small kernels ----------------
__device__ __forceinline__ void ln_core(
        float v0, float v1, float v2, float v3,
        const float* __restrict__ g, const float* __restrict__ b,
        f16* __restrict__ out, int row, float* red) {
    int t = threadIdx.x;
    float s = v0 + v1 + v2 + v3;
    float s2 = v0 * v0 + v1 * v1 + v2 * v2 + v3 * v3;
#pragma unroll
    for (int o = 32; o >= 1; o >>= 1) {
        s += __shfl_down(s, o);
        s2 += __shfl_down(s2, o);
    }
    int wid = t >> 6;
    if ((t & 63) == 0) { red[wid] = s; red[4 + wid] = s2; }
    __syncthreads();
    float ts = red[0] + red[1] + red[2] + red[3];
    float ts2 = red[4] + red[5] + red[6] + red[7];
    float mu = ts * (1.0f / 1024.0f);
    float var = ts2 * (1.0f / 1024.0f) - mu * mu;
    float rs = rsqrtf(var + 1e-5f);
    float4 gg = ((const float4*)g)[t];
    float4 bb = ((const float4*)b)[t];
    f16x4 o4;
    o4[0] = (f16)((v0 - mu) * rs * gg.x + bb.x);
    o4[1] = (f16)((v1 - mu) * rs * gg.y + bb.y);
    o4[2] = (f16)((v2 - mu) * rs * gg.z + bb.z);
    o4[3] = (f16)((v3 - mu) * rs * gg.w + bb.w);
    ((f16x4*)out)[(size_t)row * 256 + t] = o4;
}

__device__ __forceinline__ void tr_body(
        const float* __restrict__ W, f16* __restrict__ WT,
        int K, int N, int bx, int by, float* smem) {
    float (*tile)[33] = (float (*)[33])smem;
    int n0 = bx * 32, k0 = by * 32;
    int tx = threadIdx.x & 31, ty = threadIdx.x >> 5;
#pragma unroll
    for (int i = 0; i < 32; i += 8)
        tile[ty + i][tx] = W[(size_t)(k0 + ty + i) * N + n0 + tx];
    __syncthreads();
#pragma unroll
    for (int i = 0; i < 32; i += 8)
        WT[(size_t)(n0 + ty + i) * K + k0 + tx] = (f16)tile[tx][ty + i];
}

// ------- prologue: LN1 + T(Wqkv) + T(Wout) + T(W1) + T(W2), one launch -------
__global__ __launch_bounds__(256) void prologue_kernel(
        const float* __restrict__ x, const float* __restrict__ g1,
        const float* __restrict__ b1, f16* __restrict__ xn,
        const float* __restrict__ Wqkv, f16* __restrict__ wqkvT,
        const float* __restrict__ Wout, f16* __restrict__ woutT,
        const float* __restrict__ W1, f16* __restrict__ w1T,
        const float* __restrict__ W2, f16* __restrict__ w2T) {
    __shared__ float smem[32 * 33];
    int id = blockIdx.x;
    if (id < 8192) {
        const float4 v = ((const float4*)(x + (size_t)id * 1024))[threadIdx.x];
        ln_core(v.x, v.y, v.z, v.w, g1, b1, xn, id, smem);
    } else if (id < 8192 + 3072) {
        int q = id - 8192;
        tr_body(Wqkv, wqkvT, 1024, 3072, q % 96, q / 96, smem);
    } else if (id < 8192 + 3072 + 1024) {
        int q = id - (8192 + 3072);
        tr_body(Wout, woutT, 1024, 1024, q % 32, q / 32, smem);
    } else if (id < 8192 + 3072 + 1024 + 4096) {
        int q = id - (8192 + 3072 + 1024);
        tr_body(W1, w1T, 1024, 4096, q % 128, q / 128, smem);
    } else {
        int q = id - (8192 + 3072 + 1024 + 4096);
        tr_body(W2, w2T, 4096, 1024, q % 32, q / 32, smem);
    }
}

// ---------------- LN2: f16 input (x1 is exact in f16) ----------------
__global__ __launch_bounds__(256) void ln2_kernel(
        const f16* __restrict__ x, const float* __restrict__ g,
        const float* __restrict__ b, f16* __restrict__ out) {
    __shared__ float smem[8];
    int row = blockIdx.x;
    f16x4 v4 = ((const f16x4*)(x + (size_t)row * 1024))[threadIdx.x];
    ln_core((float)v4[0], (float)v4[1], (float)v4[2], (float)v4[3],
            g, b, out, row, smem);
}

// ---------------- 2-blocks/CU pipelined GEMM, supertile L2 decode (r16) ------
// BM=BN=128, BK=64, 256 threads (4 waves 2x2, wave-tile 64x64). LDS 64 KB ->
// 2 blocks/CU. Counted vmcnt(8) double-buffer. 8x8 supertile tile-order.
// EPI 0: +bias,fpq,scatter q/k(swz)/v^T(swz)
// EPI 1: +bias,fpq,+resid(f32 x),fpq -> f16 x1
// EPI 2: +bias,fpq,relu -> f16
// EPI 3: +bias,fpq,+residh(f16 x1),fpq -> f32 d_out
template <int EPI>
__global__ __launch_bounds__(256, 2) void gemmd_kernel(
        const f16* __restrict__ A, const f16* __restrict__ BT,
        int N, int K, int GM, int GN,
        const float* __restrict__ bias, const float* __restrict__ resid,
        const f16* __restrict__ residh,
        void* __restrict__ out0, f16* __restrict__ outk, f16* __restrict__ outv) {
    constexpr int ABUF = 128 * 64;               // 8192 f16 (16 KB)
    constexpr int BUFSZ = 2 * ABUF;              // A+B = 32 KB
    __shared__ f16 lds[2 * BUFSZ];               // 64 KB

    int nwg = GM * GN;
    int orig = blockIdx.x;
    int wg = (orig & 7) * (nwg >> 3) + (orig >> 3);   // contiguous wg chunk per XCD
    // supertile decode: 64 consecutive wg = 8 bm x 8 bn panels (L2-resident)
    int st = wg >> 6, in = wg & 63;
    int bm = (st % (GM >> 3)) * 8 + (in >> 3);
    int bn = (st / (GM >> 3)) * 8 + (in & 7);
    int m0 = bm * 128, n0 = bn * 128;
    int tid = threadIdx.x;
    int lane = tid & 63;
    int lr = lane & 15, lg = lane >> 4;
    int wv = tid >> 6;
    int wm = wv >> 1, wn = wv & 1;

    // staging: pre-inverse-swizzled global sources + linear LDS dests
    size_t srcA[4], srcB[4]; int dst[4];
#pragma unroll
    for (int j = 0; j < 4; ++j) {
        int row = j * 32 + (tid >> 3);
        int slot = (tid & 7) ^ (row & 7);
        srcA[j] = (size_t)(m0 + row) * K + slot * 8;
        srcB[j] = (size_t)(n0 + row) * K + slot * 8;
        dst[j] = j * 2048 + tid * 8;
    }

    // swizzled ds_read offsets (f16 elements, buffer-relative)
    int offA[2][4], offB[4][2];
#pragma unroll
    for (int i = 0; i < 4; ++i) {
        int row = wm * 64 + i * 16 + lr;
#pragma unroll
        for (int kk = 0; kk < 2; ++kk)
            offA[kk][i] = row * 64 + (((kk * 4 + lg) ^ (row & 7)) * 8);
    }
#pragma unroll
    for (int j = 0; j < 4; ++j) {
        int n = wn * 64 + j * 16 + lr;
#pragma unroll
        for (int kk = 0; kk < 2; ++kk)
            offB[j][kk] = ABUF + n * 64 + (((kk * 4 + lg) ^ (n & 7)) * 8);
    }

    f32x4 acc[4][4] = {};
    int NT = K >> 6;

    // prologue: stage tiles 0 -> buf0, 1 -> buf1 (8 gll each)
#pragma unroll
    for (int j = 0; j < 4; ++j) gll16(A + srcA[j], lds + dst[j]);
#pragma unroll
    for (int j = 0; j < 4; ++j) gll16(BT + srcB[j], lds + ABUF + dst[j]);
#pragma unroll
    for (int j = 0; j < 4; ++j) gll16(A + srcA[j] + 64, lds + BUFSZ + dst[j]);
#pragma unroll
    for (int j = 0; j < 4; ++j) gll16(BT + srcB[j] + 64, lds + BUFSZ + ABUF + dst[j]);
    waitvm<8>();                      // tile 0 landed; tile 1 in flight
    __builtin_amdgcn_s_barrier();
    __builtin_amdgcn_sched_barrier(0);

    for (int t = 0; t < NT; ++t) {
        int cur = t & 1;
        f16* Ab = lds + cur * BUFSZ;
        // ---- all A-frags + cols 0,1 B-frags ----
        f16x8 a0[4], a1[4], b00, b01, b10, b11;
#pragma unroll
        for (int i = 0; i < 4; ++i) a0[i] = *(const f16x8*)&Ab[offA[0][i]];
        b00 = *(const f16x8*)&Ab[offB[0][0]];
        b01 = *(const f16x8*)&Ab[offB[1][0]];
#pragma unroll
        for (int i = 0; i < 4; ++i) a1[i] = *(const f16x8*)&Ab[offA[1][i]];
        b10 = *(const f16x8*)&Ab[offB[0][1]];
        b11 = *(const f16x8*)&Ab[offB[1][1]];
        // ---- cols 0,1 MFMA ----
        __builtin_amdgcn_s_setprio(1);
#pragma unroll
        for (int i = 0; i < 4; ++i) {
            acc[i][0] = __builtin_amdgcn_mfma_f32_16x16x32_f16(a0[i], b00, acc[i][0], 0, 0, 0);
            acc[i][1] = __builtin_amdgcn_mfma_f32_16x16x32_f16(a0[i], b01, acc[i][1], 0, 0, 0);
        }
#pragma unroll
        for (int i = 0; i < 4; ++i) {
            acc[i][0] = __builtin_amdgcn_mfma_f32_16x16x32_f16(a1[i], b10, acc[i][0], 0, 0, 0);
            acc[i][1] = __builtin_amdgcn_mfma_f32_16x16x32_f16(a1[i], b11, acc[i][1], 0, 0, 0);
        }
        __builtin_amdgcn_s_setprio(0);
        // ---- cols 2,3 B-frags (last reads of buf cur) ----
        f16x8 b20 = *(const f16x8*)&Ab[offB[2][0]];
        f16x8 b30 = *(const f16x8*)&Ab[offB[3][0]];
        f16x8 b21 = *(const f16x8*)&Ab[offB[2][1]];
        f16x8 b31 = *(const f16x8*)&Ab[offB[3][1]];
        asm volatile("s_waitcnt lgkmcnt(0)" ::: "memory");   // buf cur fully read
        __builtin_amdgcn_sched_barrier(0);
        __builtin_amdgcn_s_barrier();                        // all waves done reading
        // ---- stage tile t+2 into buf cur (overlapped with cols 2,3) ----
        if (t + 2 < NT) {
            size_t kof = (size_t)(t + 2) << 6;
#pragma unroll
            for (int j = 0; j < 4; ++j) gll16(A + srcA[j] + kof, Ab + dst[j]);
#pragma unroll
            for (int j = 0; j < 4; ++j) gll16(BT + srcB[j] + kof, Ab + ABUF + dst[j]);
        }
        // ---- cols 2,3 MFMA ----
        __builtin_amdgcn_s_setprio(1);
#pragma unroll
        for (int i = 0; i < 4; ++i) {
            acc[i][2] = __builtin_amdgcn_mfma_f32_16x16x32_f16(a0[i], b20, acc[i][2], 0, 0, 0);
            acc[i][3] = __builtin_amdgcn_mfma_f32_16x16x32_f16(a0[i], b30, acc[i][3], 0, 0, 0);
        }
#pragma unroll
        for (int i = 0; i < 4; ++i) {
            acc[i][2] = __builtin_amdgcn_mfma_f32_16x16x32_f16(a1[i], b21, acc[i][2], 0, 0, 0);
            acc[i][3] = __builtin_amdgcn_mfma_f32_16x16x32_f16(a1[i], b31, acc[i][3], 0, 0, 0);
        }
        __builtin_amdgcn_s_setprio(0);
        // ---- tile boundary: counted wait (t+2 still in flight) ----
        if (t + 2 < NT) { waitvm<8>(); }
        else if (t + 1 < NT) { waitvm<0>(); }
        __builtin_amdgcn_sched_barrier(0);
        __builtin_amdgcn_s_barrier();
    }

    // epilogue
#pragma unroll
    for (int i = 0; i < 4; ++i) {
#pragma unroll
        for (int j = 0; j < 4; ++j) {
            int col = n0 + wn * 64 + j * 16 + lr;
            float bv = bias[col];
#pragma unroll
            for (int r = 0; r < 4; ++r) {
                int row = m0 + wm * 64 + i * 16 + lg * 4 + r;
                float val = acc[i][j][r] + bv;
                if (EPI == 0) {
                    float qv = fpq(val);
                    int part = col >> 10, wi = col & 1023;
                    int hd = wi >> 6, d = wi & 63;
                    int bb = row >> 10, ss = row & 1023;
                    size_t bh = (size_t)(bb * 16 + hd);
                    if (part == 0) {
                        ((f16*)out0)[(bh * 1024 + ss) * 64 + d] = (f16)qv;
                    } else if (part == 1) {
                        // K: [bh][kt][srow][d ^ (key(srow)<<3)]
                        outk[bh * 65536 + (ss >> 6) * 4096 + (ss & 63) * 64 + (d ^ (swzkey(ss) << 3))] = (f16)qv;
                    } else {
                        // V^T: [bh][kt][d][(srow) ^ (key(d)<<3)]
                        outv[bh * 65536 + (ss >> 6) * 4096 + d * 64 + ((ss & 63) ^ (swzkey(d) << 3))] = (f16)qv;
                    }
                } else if (EPI == 1) {
                    // x1 = fpq(x + fpq(attn)) : exact in f16 (|x1|<8, 1/256 grid)
                    float o = fpq(resid[(size_t)row * 1024 + col] + fpq(val));
                    ((f16*)out0)[(size_t)row * 1024 + col] = (f16)o;
                } else if (EPI == 2) {
                    float hv = fmaxf(fpq(val), 0.0f);
                    ((f16*)out0)[(size_t)row * N + col] = (f16)hv;
                } else {
                    float o = fpq((float)residh[(size_t)row * 1024 + col] + fpq(val));
                    ((float*)out0)[(size_t)row * 1024 + col] = o;
                }
            }
        }
    }
}

// ---------------- Fused attention: QBLK=128 (8 waves), dbuf K/V, const-shift --
__global__ __launch_bounds__(512) void attn_kernel(
        const f16* __restrict__ Q, const f16* __restrict__ Kg,
        const f16* __restrict__ Vt, f16* __restrict__ ctx) {
    int id = blockIdx.x;
    int qt = (id >> 3) & 7;
    int bh = (id >> 6) * 8 + (id & 7);   // same-bh blocks share XCD residue
    int b = bh >> 4, h = bh & 15;
    const f16* Qp = Q + ((size_t)bh * 1024 + (size_t)qt * 128) * 64;
    const f16* Kp = Kg + (size_t)bh * 65536;
    const f16* Vp = Vt + (size_t)bh * 65536;
    int t = threadIdx.x, lane = t & 63, w = t >> 6;   // w in [0,8)
    int lr = lane & 15, lg = lane >> 4;
    __shared__ f16 Ks[2][4096];
    __shared__ f16 Vs[2][4096];
    int so = t * 8;                      // 512 threads x 8 f16 = full 4096 tile

    const float L2E = 1.4426950408889634f;
    const float C0 = -24.0f * 1.4426950408889634f;

    f16x8 qf[2];
#pragma unroll
    for (int kk = 0; kk < 2; ++kk) {
        qf[kk] = *(const f16x8*)(Qp + (w * 16 + lr) * 64 + kk * 32 + lg * 8);
#pragma unroll
        for (int j = 0; j < 8; ++j) qf[kk][j] = qf[kk][j] * (f16)0.125f;
    }
    int koff[4][2], voff[4][2];
#pragma unroll
    for (int nf = 0; nf < 4; ++nf) {
        int rowv = 32 * (nf >> 1) + 8 * ((lr >> 2) ^ (2 * (nf & 1))) + 4 * (nf & 1) + (lr & 3);
#pragma unroll
        for (int kk = 0; kk < 2; ++kk)
            koff[nf][kk] = rowv * 64 + (((kk * 4 + lg) ^ swzkey(rowv)) * 8);
    }
#pragma unroll
    for (int db = 0; db < 4; ++db) {
        int d = db * 16 + lr;
#pragma unroll
        for (int kk = 0; kk < 2; ++kk)
            voff[db][kk] = d * 64 + (((kk * 4 + lg) ^ swzkey(d)) * 8);
    }

    // ---- pass 1: l = sum(exp(s - 24)); K double-buffered, counted vmcnt ----
    gll16(Kp + so, Ks[0] + so);
    float lsum = 0.0f;
    for (int kt = 0; kt < 16; ++kt) {
        int cur = kt & 1;
        if (kt < 15) {
            gll16(Kp + (kt + 1) * 4096 + so, Ks[cur ^ 1] + so);
            waitvm<1>();
        } else {
            waitvm<0>();
        }
        __builtin_amdgcn_sched_barrier(0);
        __builtin_amdgcn_s_barrier();
        f32x4 sc[4] = {};
#pragma unroll
        for (int kk = 0; kk < 2; ++kk)
#pragma unroll
            for (int nf = 0; nf < 4; ++nf) {
                f16x8 kf = *(const f16x8*)&Ks[cur][koff[nf][kk]];
                sc[nf] = __builtin_amdgcn_mfma_f32_16x16x32_f16(kf, qf[kk], sc[nf], 0, 0, 0);
            }
        float part = 0.0f;
#pragma unroll
        for (int nf = 0; nf < 4; ++nf)
#pragma unroll
            for (int r = 0; r < 4; ++r)
                part += __builtin_amdgcn_exp2f(fmaf(sc[nf][r], L2E, C0));
        lsum += part;
        __builtin_amdgcn_s_barrier();
    }
    lsum += __shfl_xor(lsum, 16);
    lsum += __shfl_xor(lsum, 32);
    float rl256 = 256.0f * __builtin_amdgcn_rcpf(lsum);

    // ---- pass 2: p = rint(e*rl256)/256, PV; K+V double-buffered ----
    f32x4 co[4] = {};
    const float inv256 = 0.00390625f;
    gll16(Kp + so, Ks[0] + so);
    gll16(Vp + so, Vs[0] + so);
    for (int kt = 0; kt < 16; ++kt) {
        int cur = kt & 1;
        if (kt < 15) {
            gll16(Kp + (kt + 1) * 4096 + so, Ks[cur ^ 1] + so);
            gll16(Vp + (kt + 1) * 4096 + so, Vs[cur ^ 1] + so);
            waitvm<2>();
        } else {
            waitvm<0>();
        }
        __builtin_amdgcn_sched_barrier(0);
        __builtin_amdgcn_s_barrier();
        f32x4 sc[4] = {};
#pragma unroll
        for (int kk = 0; kk < 2; ++kk)
#pragma unroll
            for (int nf = 0; nf < 4; ++nf) {
                f16x8 kf = *(const f16x8*)&Ks[cur][koff[nf][kk]];
                sc[nf] = __builtin_amdgcn_mfma_f32_16x16x32_f16(kf, qf[kk], sc[nf], 0, 0, 0);
            }
        uint32_t pk0[4], pk1[4];
#pragma unroll
        for (int nf = 0; nf < 4; ++nf) {
            float e0 = __builtin_amdgcn_exp2f(fmaf(sc[nf][0], L2E, C0));
            float e1 = __builtin_amdgcn_exp2f(fmaf(sc[nf][1], L2E, C0));
            float e2 = __builtin_amdgcn_exp2f(fmaf(sc[nf][2], L2E, C0));
            float e3 = __builtin_amdgcn_exp2f(fmaf(sc[nf][3], L2E, C0));
            float r0 = rintf(e0 * rl256);
            float r1 = rintf(e1 * rl256);
            float r2 = rintf(e2 * rl256);
            float r3 = rintf(e3 * rl256);
            pk0[nf] = __builtin_bit_cast(uint32_t,
                        __builtin_amdgcn_cvt_pkrtz(r0 * inv256, r1 * inv256));
            pk1[nf] = __builtin_bit_cast(uint32_t,
                        __builtin_amdgcn_cvt_pkrtz(r2 * inv256, r3 * inv256));
        }
#pragma unroll
        for (int kk = 0; kk < 2; ++kk) {
            uint4 fw;
            fw.x = pk0[2 * kk];
            fw.y = pk1[2 * kk];
            fw.z = __shfl_xor(pk0[2 * kk + 1], 32);
            fw.w = __shfl_xor(pk1[2 * kk + 1], 32);
            f16x8 pa = __builtin_bit_cast(f16x8, fw);
#pragma unroll
            for (int db = 0; db < 4; ++db) {
                f16x8 vb = *(const f16x8*)&Vs[cur][voff[db][kk]];
                co[db] = __builtin_amdgcn_mfma_f32_16x16x32_f16(pa, vb, co[db], 0, 0, 0);
            }
        }
        __builtin_amdgcn_s_barrier();
    }
#pragma unroll
    for (int db = 0; db < 4; ++db)
#pragma unroll
        for (int r = 0; r < 4; ++r) {
            int ss = qt * 128 + w * 16 + lg * 4 + r;
            ctx[((size_t)b * 1024 + ss) * 1024 + h * 64 + db * 16 + lr] = (f16)co[db][r];
        }
}

extern "C" void kernel_launch(void* const* d_in, const int* in_sizes, int n_in,
                              void* d_out, int out_size, void* d_ws, size_t ws_size,
                              hipStream_t stream) {
    const float* x     = (const float*)d_in[0];
    const float* Wqkv  = (const float*)d_in[1];
    const float* bqkv  = (const float*)d_in[2];
    const float* Wout  = (const float*)d_in[3];
    const float* bout  = (const float*)d_in[4];
    const float* W1    = (const float*)d_in[5];
    const float* b1    = (const float*)d_in[6];
    const float* W2    = (const float*)d_in[7];
    const float* b2    = (const float*)d_in[8];
    const float* g1    = (const float*)d_in[9];
    const float* beta1 = (const float*)d_in[10];
    const float* g2    = (const float*)d_in[11];
    const float* beta2 = (const float*)d_in[12];

    char* ws = (char*)d_ws;
    const size_t MB = 1ull << 20;
    f16*  q_h    = (f16*)(ws);             // 16 MB
    f16*  k_h    = (f16*)(ws + 16 * MB);   // 16 MB (swizzled tiled)
    f16*  vt_h   = (f16*)(ws + 32 * MB);   // 16 MB (V^T swizzled tiled)
    f16*  ctx_h  = (f16*)(ws + 48 * MB);   // 16 MB
    f16*  h_h    = (f16*)(ws);             // 64 MB, reuses q/k/vt/ctx after attention
    f16*  xn_h   = (f16*)(ws + 64 * MB);   // 16 MB (xn, later xn2)
    f16*  x1h    = (f16*)(ws + 80 * MB);   // 16 MB (x1 in f16 -- exact)
    f16*  w1T    = (f16*)(ws + 96 * MB);   // 8 MB
    f16*  w2T    = (f16*)(ws + 104 * MB);  // 8 MB
    f16*  wqkvT  = (f16*)(ws + 112 * MB);  // 6 MB
    f16*  woutT  = (f16*)(ws + 118 * MB);  // 2 MB   (total 120 MB)

    // --- prologue: LN1 + all four weight transposes, one launch ---
    prologue_kernel<<<8192 + 3072 + 1024 + 4096 + 4096, 256, 0, stream>>>(
        x, g1, beta1, xn_h, Wqkv, wqkvT, Wout, woutT, W1, w1T, W2, w2T);
    gemmd_kernel<0><<<1536, 256, 0, stream>>>(xn_h, wqkvT, 3072, 1024, 64, 24, bqkv, nullptr, nullptr, q_h, k_h, vt_h);
    attn_kernel<<<1024, 512, 0, stream>>>(q_h, k_h, vt_h, ctx_h);
    gemmd_kernel<1><<<512, 256, 0, stream>>>(ctx_h, woutT, 1024, 1024, 64, 8, bout, x, nullptr, x1h, nullptr, nullptr);
    // --- midlogue: LN2 on f16 x1 ---
    ln2_kernel<<<8192, 256, 0, stream>>>(x1h, g2, beta2, xn_h);
    gemmd_kernel<2><<<2048, 256, 0, stream>>>(xn_h, w1T, 4096, 1024, 64, 32, b1, nullptr, nullptr, h_h, nullptr, nullptr);
    gemmd_kernel<3><<<512, 256, 0, stream>>>(h_h, w2T, 1024, 4096, 64, 8, b2, nullptr, x1h, d_out, nullptr, nullptr);
}

// Round 20
// 348.225 us; speedup vs baseline: 1.1173x; 1.0077x over previous
//
#include <hip/hip_runtime.h>
#include <hip/hip_fp16.h>
#include <stdint.h>

typedef _Float16 f16;
typedef _Float16 f16x4 __attribute__((ext_vector_type(4)));
typedef _Float16 f16x8 __attribute__((ext_vector_type(8)));
typedef float f32x4 __attribute__((ext_vector_type(4)));

__device__ __forceinline__ float fpq(float t) {
    float r = rintf(t * 256.0f);
    r = fminf(fmaxf(r, -32768.0f), 32767.0f);
    return r * 0.00390625f;
}

// swizzle key for 64-f16 rows (8 slots of 16B): bits {0,1,3}
__device__ __forceinline__ int swzkey(int r) { return (r & 3) | ((r >> 1) & 4); }

__device__ __forceinline__ void gll16(const f16* g, f16* l) {
    __builtin_amdgcn_global_load_lds(
        (const __attribute__((address_space(1))) uint32_t*)g,
        (__attribute__((address_space(3))) uint32_t*)l, 16, 0, 0);
}

template <int N> __device__ __forceinline__ void waitvm() {
    if constexpr (N == 0)      asm volatile("s_waitcnt vmcnt(0)" ::: "memory");
    else if constexpr (N == 1) asm volatile("s_waitcnt vmcnt(1)" ::: "memory");
    else if constexpr (N == 2) asm volatile("s_waitcnt vmcnt(2)" ::: "memory");
    else if constexpr (N == 4) asm volatile("s_waitcnt vmcnt(4)" ::: "memory");
    else if constexpr (N == 6) asm volatile("s_waitcnt vmcnt(6)" ::: "memory");
    else                       asm volatile("s_waitcnt vmcnt(8)" ::: "memory");
}

// ---------------- device bodies for fused small kernels ----------------
__device__ __forceinline__ void ln_core(
        float v0, float v1, float v2, float v3,
        const float* __restrict__ g, const float* __restrict__ b,
        f16* __restrict__ out, int row, float* red) {
    int t = threadIdx.x;
    float s = v0 + v1 + v2 + v3;
    float s2 = v0 * v0 + v1 * v1 + v2 * v2 + v3 * v3;
#pragma unroll
    for (int o = 32; o >= 1; o >>= 1) {
        s += __shfl_down(s, o);
        s2 += __shfl_down(s2, o);
    }
    int wid = t >> 6;
    if ((t & 63) == 0) { red[wid] = s; red[4 + wid] = s2; }
    __syncthreads();
    float ts = red[0] + red[1] + red[2] + red[3];
    float ts2 = red[4] + red[5] + red[6] + red[7];
    float mu = ts * (1.0f / 1024.0f);
    float var = ts2 * (1.0f / 1024.0f) - mu * mu;
    float rs = rsqrtf(var + 1e-5f);
    float4 gg = ((const float4*)g)[t];
    float4 bb = ((const float4*)b)[t];
    f16x4 o4;
    o4[0] = (f16)((v0 - mu) * rs * gg.x + bb.x);
    o4[1] = (f16)((v1 - mu) * rs * gg.y + bb.y);
    o4[2] = (f16)((v2 - mu) * rs * gg.z + bb.z);
    o4[3] = (f16)((v3 - mu) * rs * gg.w + bb.w);
    ((f16x4*)out)[(size_t)row * 256 + t] = o4;
}

__device__ __forceinline__ void tr_body(
        const float* __restrict__ W, f16* __restrict__ WT,
        int K, int N, int bx, int by, float* smem) {
    float (*tile)[33] = (float (*)[33])smem;
    int n0 = bx * 32, k0 = by * 32;
    int tx = threadIdx.x & 31, ty = threadIdx.x >> 5;
#pragma unroll
    for (int i = 0; i < 32; i += 8)
        tile[ty + i][tx] = W[(size_t)(k0 + ty + i) * N + n0 + tx];
    __syncthreads();
#pragma unroll
    for (int i = 0; i < 32; i += 8)
        WT[(size_t)(n0 + ty + i) * K + k0 + tx] = (f16)tile[tx][ty + i];
}

// ------- prologue: LN1 + T(Wqkv) + T(Wout) + T(W1) + T(W2), one launch -------
__global__ __launch_bounds__(256) void prologue_kernel(
        const float* __restrict__ x, const float* __restrict__ g1,
        const float* __restrict__ b1, f16* __restrict__ xn,
        const float* __restrict__ Wqkv, f16* __restrict__ wqkvT,
        const float* __restrict__ Wout, f16* __restrict__ woutT,
        const float* __restrict__ W1, f16* __restrict__ w1T,
        const float* __restrict__ W2, f16* __restrict__ w2T) {
    __shared__ float smem[32 * 33];
    int id = blockIdx.x;
    if (id < 8192) {
        const float4 v = ((const float4*)(x + (size_t)id * 1024))[threadIdx.x];
        ln_core(v.x, v.y, v.z, v.w, g1, b1, xn, id, smem);
    } else if (id < 8192 + 3072) {
        int q = id - 8192;
        tr_body(Wqkv, wqkvT, 1024, 3072, q % 96, q / 96, smem);
    } else if (id < 8192 + 3072 + 1024) {
        int q = id - (8192 + 3072);
        tr_body(Wout, woutT, 1024, 1024, q % 32, q / 32, smem);
    } else if (id < 8192 + 3072 + 1024 + 4096) {
        int q = id - (8192 + 3072 + 1024);
        tr_body(W1, w1T, 1024, 4096, q % 128, q / 128, smem);
    } else {
        int q = id - (8192 + 3072 + 1024 + 4096);
        tr_body(W2, w2T, 4096, 1024, q % 32, q / 32, smem);
    }
}

// ---------------- LN2: f16 input (x1 is exact in f16) ----------------
__global__ __launch_bounds__(256) void ln2_kernel(
        const f16* __restrict__ x, const float* __restrict__ g,
        const float* __restrict__ b, f16* __restrict__ out) {
    __shared__ float smem[8];
    int row = blockIdx.x;
    f16x4 v4 = ((const f16x4*)(x + (size_t)row * 1024))[threadIdx.x];
    ln_core((float)v4[0], (float)v4[1], (float)v4[2], (float)v4[3],
            g, b, out, row, smem);
}

// ---------------- 2-blocks/CU pipelined GEMM, supertile L2 decode (r16) ------
// BM=BN=128, BK=64, 256 threads (4 waves 2x2, wave-tile 64x64). LDS 64 KB ->
// 2 blocks/CU. Counted vmcnt(8) double-buffer. 8x8 supertile tile-order.
// EPI 0: +bias,fpq,scatter q/k(swz)/v^T(swz)
// EPI 1: +bias,fpq,+resid(f32 x),fpq -> f16 x1
// EPI 2: +bias,fpq,relu -> f16
// EPI 3: +bias,fpq,+residh(f16 x1),fpq -> f32 d_out
template <int EPI>
__global__ __launch_bounds__(256, 2) void gemmd_kernel(
        const f16* __restrict__ A, const f16* __restrict__ BT,
        int N, int K, int GM, int GN,
        const float* __restrict__ bias, const float* __restrict__ resid,
        const f16* __restrict__ residh,
        void* __restrict__ out0, f16* __restrict__ outk, f16* __restrict__ outv) {
    constexpr int ABUF = 128 * 64;               // 8192 f16 (16 KB)
    constexpr int BUFSZ = 2 * ABUF;              // A+B = 32 KB
    __shared__ f16 lds[2 * BUFSZ];               // 64 KB

    int nwg = GM * GN;
    int orig = blockIdx.x;
    int wg = (orig & 7) * (nwg >> 3) + (orig >> 3);   // contiguous wg chunk per XCD
    // supertile decode: 64 consecutive wg = 8 bm x 8 bn panels (L2-resident)
    int st = wg >> 6, in = wg & 63;
    int bm = (st % (GM >> 3)) * 8 + (in >> 3);
    int bn = (st / (GM >> 3)) * 8 + (in & 7);
    int m0 = bm * 128, n0 = bn * 128;
    int tid = threadIdx.x;
    int lane = tid & 63;
    int lr = lane & 15, lg = lane >> 4;
    int wv = tid >> 6;
    int wm = wv >> 1, wn = wv & 1;

    // staging: pre-inverse-swizzled global sources + linear LDS dests
    size_t srcA[4], srcB[4]; int dst[4];
#pragma unroll
    for (int j = 0; j < 4; ++j) {
        int row = j * 32 + (tid >> 3);
        int slot = (tid & 7) ^ (row & 7);
        srcA[j] = (size_t)(m0 + row) * K + slot * 8;
        srcB[j] = (size_t)(n0 + row) * K + slot * 8;
        dst[j] = j * 2048 + tid * 8;
    }

    // swizzled ds_read offsets (f16 elements, buffer-relative)
    int offA[2][4], offB[4][2];
#pragma unroll
    for (int i = 0; i < 4; ++i) {
        int row = wm * 64 + i * 16 + lr;
#pragma unroll
        for (int kk = 0; kk < 2; ++kk)
            offA[kk][i] = row * 64 + (((kk * 4 + lg) ^ (row & 7)) * 8);
    }
#pragma unroll
    for (int j = 0; j < 4; ++j) {
        int n = wn * 64 + j * 16 + lr;
#pragma unroll
        for (int kk = 0; kk < 2; ++kk)
            offB[j][kk] = ABUF + n * 64 + (((kk * 4 + lg) ^ (n & 7)) * 8);
    }

    f32x4 acc[4][4] = {};
    int NT = K >> 6;

    // prologue: stage tiles 0 -> buf0, 1 -> buf1 (8 gll each)
#pragma unroll
    for (int j = 0; j < 4; ++j) gll16(A + srcA[j], lds + dst[j]);
#pragma unroll
    for (int j = 0; j < 4; ++j) gll16(BT + srcB[j], lds + ABUF + dst[j]);
#pragma unroll
    for (int j = 0; j < 4; ++j) gll16(A + srcA[j] + 64, lds + BUFSZ + dst[j]);
#pragma unroll
    for (int j = 0; j < 4; ++j) gll16(BT + srcB[j] + 64, lds + BUFSZ + ABUF + dst[j]);
    waitvm<8>();                      // tile 0 landed; tile 1 in flight
    __builtin_amdgcn_s_barrier();
    __builtin_amdgcn_sched_barrier(0);

    for (int t = 0; t < NT; ++t) {
        int cur = t & 1;
        f16* Ab = lds + cur * BUFSZ;
        // ---- all A-frags + cols 0,1 B-frags ----
        f16x8 a0[4], a1[4], b00, b01, b10, b11;
#pragma unroll
        for (int i = 0; i < 4; ++i) a0[i] = *(const f16x8*)&Ab[offA[0][i]];
        b00 = *(const f16x8*)&Ab[offB[0][0]];
        b01 = *(const f16x8*)&Ab[offB[1][0]];
#pragma unroll
        for (int i = 0; i < 4; ++i) a1[i] = *(const f16x8*)&Ab[offA[1][i]];
        b10 = *(const f16x8*)&Ab[offB[0][1]];
        b11 = *(const f16x8*)&Ab[offB[1][1]];
        // ---- cols 0,1 MFMA ----
        __builtin_amdgcn_s_setprio(1);
#pragma unroll
        for (int i = 0; i < 4; ++i) {
            acc[i][0] = __builtin_amdgcn_mfma_f32_16x16x32_f16(a0[i], b00, acc[i][0], 0, 0, 0);
            acc[i][1] = __builtin_amdgcn_mfma_f32_16x16x32_f16(a0[i], b01, acc[i][1], 0, 0, 0);
        }
#pragma unroll
        for (int i = 0; i < 4; ++i) {
            acc[i][0] = __builtin_amdgcn_mfma_f32_16x16x32_f16(a1[i], b10, acc[i][0], 0, 0, 0);
            acc[i][1] = __builtin_amdgcn_mfma_f32_16x16x32_f16(a1[i], b11, acc[i][1], 0, 0, 0);
        }
        __builtin_amdgcn_s_setprio(0);
        // ---- cols 2,3 B-frags (last reads of buf cur) ----
        f16x8 b20 = *(const f16x8*)&Ab[offB[2][0]];
        f16x8 b30 = *(const f16x8*)&Ab[offB[3][0]];
        f16x8 b21 = *(const f16x8*)&Ab[offB[2][1]];
        f16x8 b31 = *(const f16x8*)&Ab[offB[3][1]];
        asm volatile("s_waitcnt lgkmcnt(0)" ::: "memory");   // buf cur fully read
        __builtin_amdgcn_sched_barrier(0);
        __builtin_amdgcn_s_barrier();                        // all waves done reading
        // ---- stage tile t+2 into buf cur (overlapped with cols 2,3) ----
        if (t + 2 < NT) {
            size_t kof = (size_t)(t + 2) << 6;
#pragma unroll
            for (int j = 0; j < 4; ++j) gll16(A + srcA[j] + kof, Ab + dst[j]);
#pragma unroll
            for (int j = 0; j < 4; ++j) gll16(BT + srcB[j] + kof, Ab + ABUF + dst[j]);
        }
        // ---- cols 2,3 MFMA ----
        __builtin_amdgcn_s_setprio(1);
#pragma unroll
        for (int i = 0; i < 4; ++i) {
            acc[i][2] = __builtin_amdgcn_mfma_f32_16x16x32_f16(a0[i], b20, acc[i][2], 0, 0, 0);
            acc[i][3] = __builtin_amdgcn_mfma_f32_16x16x32_f16(a0[i], b30, acc[i][3], 0, 0, 0);
        }
#pragma unroll
        for (int i = 0; i < 4; ++i) {
            acc[i][2] = __builtin_amdgcn_mfma_f32_16x16x32_f16(a1[i], b21, acc[i][2], 0, 0, 0);
            acc[i][3] = __builtin_amdgcn_mfma_f32_16x16x32_f16(a1[i], b31, acc[i][3], 0, 0, 0);
        }
        __builtin_amdgcn_s_setprio(0);
        // ---- tile boundary: counted wait (t+2 still in flight) ----
        if (t + 2 < NT) { waitvm<8>(); }
        else if (t + 1 < NT) { waitvm<0>(); }
        __builtin_amdgcn_sched_barrier(0);
        __builtin_amdgcn_s_barrier();
    }

    // epilogue
#pragma unroll
    for (int i = 0; i < 4; ++i) {
#pragma unroll
        for (int j = 0; j < 4; ++j) {
            int col = n0 + wn * 64 + j * 16 + lr;
            float bv = bias[col];
#pragma unroll
            for (int r = 0; r < 4; ++r) {
                int row = m0 + wm * 64 + i * 16 + lg * 4 + r;
                float val = acc[i][j][r] + bv;
                if (EPI == 0) {
                    float qv = fpq(val);
                    int part = col >> 10, wi = col & 1023;
                    int hd = wi >> 6, d = wi & 63;
                    int bb = row >> 10, ss = row & 1023;
                    size_t bh = (size_t)(bb * 16 + hd);
                    if (part == 0) {
                        ((f16*)out0)[(bh * 1024 + ss) * 64 + d] = (f16)qv;
                    } else if (part == 1) {
                        // K: [bh][kt][srow][d ^ (key(srow)<<3)]
                        outk[bh * 65536 + (ss >> 6) * 4096 + (ss & 63) * 64 + (d ^ (swzkey(ss) << 3))] = (f16)qv;
                    } else {
                        // V^T: [bh][kt][d][(srow) ^ (key(d)<<3)]
                        outv[bh * 65536 + (ss >> 6) * 4096 + d * 64 + ((ss & 63) ^ (swzkey(d) << 3))] = (f16)qv;
                    }
                } else if (EPI == 1) {
                    // x1 = fpq(x + fpq(attn)) : exact in f16 (|x1|<8, 1/256 grid)
                    float o = fpq(resid[(size_t)row * 1024 + col] + fpq(val));
                    ((f16*)out0)[(size_t)row * 1024 + col] = (f16)o;
                } else if (EPI == 2) {
                    float hv = fmaxf(fpq(val), 0.0f);
                    ((f16*)out0)[(size_t)row * N + col] = (f16)hv;
                } else {
                    float o = fpq((float)residh[(size_t)row * 1024 + col] + fpq(val));
                    ((float*)out0)[(size_t)row * 1024 + col] = o;
                }
            }
        }
    }
}

// ---------------- Fused attention: QBLK=128 (8 waves), dbuf K/V, const-shift --
// Pass 2 folds normalization into the exponent (C2 = C0 + 8 - log2(lsum)) and
// keeps P as small integers in f16; PV output scaled by 1/256 at the epilogue.
__global__ __launch_bounds__(512) void attn_kernel(
        const f16* __restrict__ Q, const f16* __restrict__ Kg,
        const f16* __restrict__ Vt, f16* __restrict__ ctx) {
    int id = blockIdx.x;
    int qt = (id >> 3) & 7;
    int bh = (id >> 6) * 8 + (id & 7);   // same-bh blocks share XCD residue
    int b = bh >> 4, h = bh & 15;
    const f16* Qp = Q + ((size_t)bh * 1024 + (size_t)qt * 128) * 64;
    const f16* Kp = Kg + (size_t)bh * 65536;
    const f16* Vp = Vt + (size_t)bh * 65536;
    int t = threadIdx.x, lane = t & 63, w = t >> 6;   // w in [0,8)
    int lr = lane & 15, lg = lane >> 4;
    __shared__ f16 Ks[2][4096];
    __shared__ f16 Vs[2][4096];
    int so = t * 8;                      // 512 threads x 8 f16 = full 4096 tile

    const float L2E = 1.4426950408889634f;
    const float C0 = -24.0f * 1.4426950408889634f;

    f16x8 qf[2];
#pragma unroll
    for (int kk = 0; kk < 2; ++kk) {
        qf[kk] = *(const f16x8*)(Qp + (w * 16 + lr) * 64 + kk * 32 + lg * 8);
#pragma unroll
        for (int j = 0; j < 8; ++j) qf[kk][j] = qf[kk][j] * (f16)0.125f;
    }
    int koff[4][2], voff[4][2];
#pragma unroll
    for (int nf = 0; nf < 4; ++nf) {
        int rowv = 32 * (nf >> 1) + 8 * ((lr >> 2) ^ (2 * (nf & 1))) + 4 * (nf & 1) + (lr & 3);
#pragma unroll
        for (int kk = 0; kk < 2; ++kk)
            koff[nf][kk] = rowv * 64 + (((kk * 4 + lg) ^ swzkey(rowv)) * 8);
    }
#pragma unroll
    for (int db = 0; db < 4; ++db) {
        int d = db * 16 + lr;
#pragma unroll
        for (int kk = 0; kk < 2; ++kk)
            voff[db][kk] = d * 64 + (((kk * 4 + lg) ^ swzkey(d)) * 8);
    }

    // ---- pass 1: l = sum(exp(s - 24)); K double-buffered, counted vmcnt ----
    gll16(Kp + so, Ks[0] + so);
    float lsum = 0.0f;
    for (int kt = 0; kt < 16; ++kt) {
        int cur = kt & 1;
        if (kt < 15) {
            gll16(Kp + (kt + 1) * 4096 + so, Ks[cur ^ 1] + so);
            waitvm<1>();
        } else {
            waitvm<0>();
        }
        __builtin_amdgcn_sched_barrier(0);
        __builtin_amdgcn_s_barrier();
        f32x4 sc[4] = {};
#pragma unroll
        for (int kk = 0; kk < 2; ++kk)
#pragma unroll
            for (int nf = 0; nf < 4; ++nf) {
                f16x8 kf = *(const f16x8*)&Ks[cur][koff[nf][kk]];
                sc[nf] = __builtin_amdgcn_mfma_f32_16x16x32_f16(kf, qf[kk], sc[nf], 0, 0, 0);
            }
        float part = 0.0f;
#pragma unroll
        for (int nf = 0; nf < 4; ++nf)
#pragma unroll
            for (int r = 0; r < 4; ++r)
                part += __builtin_amdgcn_exp2f(fmaf(sc[nf][r], L2E, C0));
        lsum += part;
        __builtin_amdgcn_s_barrier();
    }
    lsum += __shfl_xor(lsum, 16);
    lsum += __shfl_xor(lsum, 32);
    // fold normalization into exponent: rint(256*e/l) = rint(exp2(s*L2E + C2))
    float c2 = (C0 + 8.0f) - __log2f(lsum);

    // ---- pass 2: P = rint(exp2(s*L2E + C2)) (int in f16), PV; scale at end ----
    f32x4 co[4] = {};
    const float inv256 = 0.00390625f;
    gll16(Kp + so, Ks[0] + so);
    gll16(Vp + so, Vs[0] + so);
    for (int kt = 0; kt < 16; ++kt) {
        int cur = kt & 1;
        if (kt < 15) {
            gll16(Kp + (kt + 1) * 4096 + so, Ks[cur ^ 1] + so);
            gll16(Vp + (kt + 1) * 4096 + so, Vs[cur ^ 1] + so);
            waitvm<2>();
        } else {
            waitvm<0>();
        }
        __builtin_amdgcn_sched_barrier(0);
        __builtin_amdgcn_s_barrier();
        f32x4 sc[4] = {};
#pragma unroll
        for (int kk = 0; kk < 2; ++kk)
#pragma unroll
            for (int nf = 0; nf < 4; ++nf) {
                f16x8 kf = *(const f16x8*)&Ks[cur][koff[nf][kk]];
                sc[nf] = __builtin_amdgcn_mfma_f32_16x16x32_f16(kf, qf[kk], sc[nf], 0, 0, 0);
            }
        uint32_t pk0[4], pk1[4];
#pragma unroll
        for (int nf = 0; nf < 4; ++nf) {
            float r0 = rintf(__builtin_amdgcn_exp2f(fmaf(sc[nf][0], L2E, c2)));
            float r1 = rintf(__builtin_amdgcn_exp2f(fmaf(sc[nf][1], L2E, c2)));
            float r2 = rintf(__builtin_amdgcn_exp2f(fmaf(sc[nf][2], L2E, c2)));
            float r3 = rintf(__builtin_amdgcn_exp2f(fmaf(sc[nf][3], L2E, c2)));
            pk0[nf] = __builtin_bit_cast(uint32_t, __builtin_amdgcn_cvt_pkrtz(r0, r1));
            pk1[nf] = __builtin_bit_cast(uint32_t, __builtin_amdgcn_cvt_pkrtz(r2, r3));
        }
#pragma unroll
        for (int kk = 0; kk < 2; ++kk) {
            uint4 fw;
            fw.x = pk0[2 * kk];
            fw.y = pk1[2 * kk];
            fw.z = __shfl_xor(pk0[2 * kk + 1], 32);
            fw.w = __shfl_xor(pk1[2 * kk + 1], 32);
            f16x8 pa = __builtin_bit_cast(f16x8, fw);
#pragma unroll
            for (int db = 0; db < 4; ++db) {
                f16x8 vb = *(const f16x8*)&Vs[cur][voff[db][kk]];
                co[db] = __builtin_amdgcn_mfma_f32_16x16x32_f16(pa, vb, co[db], 0, 0, 0);
            }
        }
        __builtin_amdgcn_s_barrier();
    }
#pragma unroll
    for (int db = 0; db < 4; ++db)
#pragma unroll
        for (int r = 0; r < 4; ++r) {
            int ss = qt * 128 + w * 16 + lg * 4 + r;
            ctx[((size_t)b * 1024 + ss) * 1024 + h * 64 + db * 16 + lr] =
                (f16)(co[db][r] * inv256);
        }
}

extern "C" void kernel_launch(void* const* d_in, const int* in_sizes, int n_in,
                              void* d_out, int out_size, void* d_ws, size_t ws_size,
                              hipStream_t stream) {
    const float* x     = (const float*)d_in[0];
    const float* Wqkv  = (const float*)d_in[1];
    const float* bqkv  = (const float*)d_in[2];
    const float* Wout  = (const float*)d_in[3];
    const float* bout  = (const float*)d_in[4];
    const float* W1    = (const float*)d_in[5];
    const float* b1    = (const float*)d_in[6];
    const float* W2    = (const float*)d_in[7];
    const float* b2    = (const float*)d_in[8];
    const float* g1    = (const float*)d_in[9];
    const float* beta1 = (const float*)d_in[10];
    const float* g2    = (const float*)d_in[11];
    const float* beta2 = (const float*)d_in[12];

    char* ws = (char*)d_ws;
    const size_t MB = 1ull << 20;
    f16*  q_h    = (f16*)(ws);             // 16 MB
    f16*  k_h    = (f16*)(ws + 16 * MB);   // 16 MB (swizzled tiled)
    f16*  vt_h   = (f16*)(ws + 32 * MB);   // 16 MB (V^T swizzled tiled)
    f16*  ctx_h  = (f16*)(ws + 48 * MB);   // 16 MB
    f16*  h_h    = (f16*)(ws);             // 64 MB, reuses q/k/vt/ctx after attention
    f16*  xn_h   = (f16*)(ws + 64 * MB);   // 16 MB (xn, later xn2)
    f16*  x1h    = (f16*)(ws + 80 * MB);   // 16 MB (x1 in f16 -- exact)
    f16*  w1T    = (f16*)(ws + 96 * MB);   // 8 MB
    f16*  w2T    = (f16*)(ws + 104 * MB);  // 8 MB
    f16*  wqkvT  = (f16*)(ws + 112 * MB);  // 6 MB
    f16*  woutT  = (f16*)(ws + 118 * MB);  // 2 MB   (total 120 MB)

    // --- prologue: LN1 + all four weight transposes, one launch ---
    prologue_kernel<<<8192 + 3072 + 1024 + 4096 + 4096, 256, 0, stream>>>(
        x, g1, beta1, xn_h, Wqkv, wqkvT, Wout, woutT, W1, w1T, W2, w2T);
    gemmd_kernel<0><<<1536, 256, 0, stream>>>(xn_h, wqkvT, 3072, 1024, 64, 24, bqkv, nullptr, nullptr, q_h, k_h, vt_h);
    attn_kernel<<<1024, 512, 0, stream>>>(q_h, k_h, vt_h, ctx_h);
    gemmd_kernel<1><<<512, 256, 0, stream>>>(ctx_h, woutT, 1024, 1024, 64, 8, bout, x, nullptr, x1h, nullptr, nullptr);
    // --- midlogue: LN2 on f16 x1 ---
    ln2_kernel<<<8192, 256, 0, stream>>>(x1h, g2, beta2, xn_h);
    gemmd_kernel<2><<<2048, 256, 0, stream>>>(xn_h, w1T, 4096, 1024, 64, 32, b1, nullptr, nullptr, h_h, nullptr, nullptr);
    gemmd_kernel<3><<<512, 256, 0, stream>>>(h_h, w2T, 1024, 4096, 64, 8, b2, nullptr, x1h, d_out, nullptr, nullptr);
}